// Round 15
// baseline (484.244 us; speedup 1.0000x reference)
//
#include <hip/hip_runtime.h>

#define NN    50000
#define IN_CH 512
#define HID   256
#define PJ    1024
#define FN    50000.0f
#define KTP   50176          // padded node-dim for ht (784*64)
#define NCH   98
#define CHK   512

typedef __attribute__((ext_vector_type(4)))  float f32x4;
typedef __attribute__((ext_vector_type(16))) float f32x16;
typedef __attribute__((ext_vector_type(4)))  int   i32x4;
typedef __attribute__((ext_vector_type(8)))  unsigned short u16x8;

__device__ inline void mfma16(f32x4& c, i32x4 a, i32x4 b){
  asm("v_mfma_f32_16x16x32_bf16 %0, %1, %2, %0" : "+v"(c) : "v"(a), "v"(b));
}
__device__ inline void mfma32(f32x16& c, i32x4 a, i32x4 b){
  asm("v_mfma_f32_32x32x16_bf16 %0, %1, %2, %0" : "+v"(c) : "v"(a), "v"(b));
}

__device__ inline unsigned short f2bf(float f){
  unsigned int u = __builtin_bit_cast(unsigned int, f);
  unsigned int r = (u + 0x7fffu + ((u >> 16) & 1u)) >> 16;
  return (unsigned short)r;
}
__device__ inline float bf2f(unsigned short u){
  unsigned int x = ((unsigned int)u) << 16;
  return __builtin_bit_cast(float, x);
}

__device__ inline float wave_reduce(float v){
  #pragma unroll
  for(int o=32;o>0;o>>=1) v += __shfl_down(v,o,64);
  return v;
}
__device__ inline float block_reduce(float v, float* sh4){
  v = wave_reduce(v);
  int lane = threadIdx.x & 63, wv = threadIdx.x >> 6;
  if(lane==0) sh4[wv] = v;
  __syncthreads();
  float r = sh4[0]+sh4[1]+sh4[2]+sh4[3];
  __syncthreads();
  return r;
}

// ---- fc_w [512][256] fp32 -> FWT2 tiled bf16 [kb=8][256 n][64 k] ----------
__global__ void wconv(const float* __restrict__ w, unsigned short* __restrict__ wt){
  int idx = blockIdx.x*256 + threadIdx.x;
  if(idx >= IN_CH*HID) return;
  int k = idx >> 8, n = idx & 255;
  wt[((size_t)(k>>6)*256 + n)*64 + (k&63)] = f2bf(w[idx]);
}

// ---------------- FFN + fused LN + ReLU -> hb bf16 (R7/R10-proven) ---------
__global__ __launch_bounds__(512)
void ffn_gemm(const float* __restrict__ X, const unsigned short* __restrict__ FWT2,
              const float* __restrict__ bias, const float* __restrict__ g,
              const float* __restrict__ b2, unsigned short* __restrict__ hbo){
  __shared__ __align__(16) unsigned char smem[55296];
  unsigned short (*as)[72] = (unsigned short(*)[72])smem;            // 128x72
  unsigned short (*bs)[72] = (unsigned short(*)[72])(smem + 18432);  // 256x72
  int t = threadIdx.x;
  int bm = blockIdx.x*128;
  int w = t>>6, lane = t&63;
  int wr = w>>2, wc = w&3;
  f32x4 acc[4][4];
  #pragma unroll
  for(int i=0;i<4;i++)
    #pragma unroll
    for(int j=0;j<4;j++) acc[i][j] = (f32x4){0.f,0.f,0.f,0.f};

  int ar = t>>2, aq = t&3;
  bool aok = (bm+ar) < NN;
  const float* xsrc = X + (size_t)(bm+ar)*IN_CH + aq*16;
  ushort4 aregs[4];
  u16x8 bregs[4];
  #pragma unroll
  for(int i=0;i<4;i++){
    float4 v = aok ? *(const float4*)(xsrc + i*4) : make_float4(0.f,0.f,0.f,0.f);
    ushort4 u; u.x=f2bf(v.x); u.y=f2bf(v.y); u.z=f2bf(v.z); u.w=f2bf(v.w);
    aregs[i]=u;
  }
  #pragma unroll
  for(int i=0;i<4;i++) bregs[i] = *(const u16x8*)(FWT2 + (size_t)t*32 + i*8);

  for(int kb=0;kb<8;kb++){
    __syncthreads();
    #pragma unroll
    for(int i=0;i<4;i++) *(ushort4*)&as[ar][aq*16 + i*4] = aregs[i];
    { int n = t>>1, q = t&1;
      #pragma unroll
      for(int i=0;i<4;i++) *(u16x8*)&bs[n][q*32 + i*8] = bregs[i];
    }
    __syncthreads();
    if(kb<7){
      const float* xs2 = xsrc + (kb+1)*64;
      #pragma unroll
      for(int i=0;i<4;i++){
        float4 v = aok ? *(const float4*)(xs2 + i*4) : make_float4(0.f,0.f,0.f,0.f);
        ushort4 u; u.x=f2bf(v.x); u.y=f2bf(v.y); u.z=f2bf(v.z); u.w=f2bf(v.w);
        aregs[i]=u;
      }
      const unsigned short* bsrc = FWT2 + (size_t)(kb+1)*16384 + (size_t)t*32;
      #pragma unroll
      for(int i=0;i<4;i++) bregs[i] = *(const u16x8*)(bsrc + i*8);
    }
    #pragma unroll
    for(int ks=0;ks<2;ks++){
      i32x4 af[4], bfv[4];
      #pragma unroll
      for(int i=0;i<4;i++) af[i]  = *(const i32x4*)&as[wr*64 + i*16 + (lane&15)][ks*32 + (lane>>4)*8];
      #pragma unroll
      for(int j=0;j<4;j++) bfv[j] = *(const i32x4*)&bs[wc*64 + j*16 + (lane&15)][ks*32 + (lane>>4)*8];
      #pragma unroll
      for(int i=0;i<4;i++)
        #pragma unroll
        for(int j=0;j<4;j++) mfma16(acc[i][j], af[i], bfv[j]);
    }
  }
  __syncthreads();
  int cb = wc*64;
  #pragma unroll
  for(int j=0;j<4;j++){
    float bb = bias[cb + j*16 + (lane&15)];
    #pragma unroll
    for(int i=0;i<4;i++)
      #pragma unroll
      for(int r=0;r<4;r++) acc[i][j][r] += bb;
  }
  float (*lnp)[4][2] = (float(*)[4][2])smem;
  float (*lnstat)[2] = (float(*)[2])(smem + 4096);
  #pragma unroll
  for(int i=0;i<4;i++)
    #pragma unroll
    for(int r=0;r<4;r++){
      float s=0.f, q=0.f;
      #pragma unroll
      for(int j=0;j<4;j++){ float a=acc[i][j][r]; s+=a; q+=a*a; }
      #pragma unroll
      for(int m=1;m<16;m<<=1){ s += __shfl_xor(s,m,64); q += __shfl_xor(q,m,64); }
      if((lane&15)==0){
        int row = wr*64 + i*16 + (lane>>4)*4 + r;
        lnp[row][wc][0]=s; lnp[row][wc][1]=q;
      }
    }
  __syncthreads();
  if(t<128){
    float s=0.f,q=0.f;
    #pragma unroll
    for(int c=0;c<4;c++){ s+=lnp[t][c][0]; q+=lnp[t][c][1]; }
    float mu = s*(1.f/HID);
    float var = q*(1.f/HID) - mu*mu;
    lnstat[t][0]=mu; lnstat[t][1]=rsqrtf(var+1e-5f);
  }
  __syncthreads();
  #pragma unroll
  for(int j=0;j<4;j++){
    int col = cb + j*16 + (lane&15);
    float gg = g[col], bb = b2[col];
    #pragma unroll
    for(int i=0;i<4;i++)
      #pragma unroll
      for(int r=0;r<4;r++){
        int row = wr*64 + i*16 + (lane>>4)*4 + r;
        int grow = bm + row;
        if(grow<NN){
          float y = fmaxf((acc[i][j][r]-lnstat[row][0])*lnstat[row][1]*gg + bb, 0.f);
          hbo[(size_t)grow*HID + col] = f2bf(y);
        }
      }
  }
}

// ------- LN+ReLU (post-attn): bf16 in -> bf16 and/or fp32 out; 32 rows/blk -
__global__ void ln_relu2b(const unsigned short* __restrict__ in, const float* __restrict__ g,
                          const float* __restrict__ b, unsigned short* __restrict__ outb,
                          float* __restrict__ outf, int M){
  int lane = threadIdx.x & 63, wv = threadIdx.x >> 6;
  int base = blockIdx.x*32 + wv*8;
  for(int rr=0; rr<8; rr++){
    int row = base + rr;
    if(row>=M) break;
    const unsigned short* rp = in + (size_t)row*HID;
    ushort4 hv = *(const ushort4*)(rp + lane*4);
    float v[4] = {bf2f(hv.x), bf2f(hv.y), bf2f(hv.z), bf2f(hv.w)};
    float sum = v[0]+v[1]+v[2]+v[3];
    float sq  = v[0]*v[0]+v[1]*v[1]+v[2]*v[2]+v[3]*v[3];
    sum = wave_reduce(sum); sq = wave_reduce(sq);
    sum = __shfl(sum,0,64); sq = __shfl(sq,0,64);
    float mu = sum*(1.f/HID);
    float var = sq*(1.f/HID) - mu*mu;
    float rs = rsqrtf(var + 1e-5f);
    float y[4];
    #pragma unroll
    for(int j=0;j<4;j++){ int c=lane*4+j;
      y[j] = fmaxf((v[j]-mu)*rs*g[c] + b[c], 0.f); }
    if(outb){
      ushort4 u; u.x=f2bf(y[0]); u.y=f2bf(y[1]); u.z=f2bf(y[2]); u.w=f2bf(y[3]);
      *(ushort4*)(outb + (size_t)row*HID + lane*4) = u;
    }
    if(outf){
      float4 f; f.x=y[0]; f.y=y[1]; f.z=y[2]; f.w=y[3];
      *(float4*)(outf + (size_t)row*HID + lane*4) = f;
    }
  }
}

// ---- hb [NN][256] bf16 -> ht [256][KTP] bf16 (zero-padded); 4 tiles/blk ---
__global__ __launch_bounds__(256)
void transpose_h(const unsigned short* __restrict__ hb, unsigned short* __restrict__ ht){
  __shared__ unsigned short ts[64][72];
  int r0 = blockIdx.x*64;
  int t = threadIdx.x;
  for(int cq=0; cq<4; cq++){
    int c0 = cq*64;
    { int r = t&63, q = t>>6;
      #pragma unroll
      for(int i=0;i<2;i++){
        int c = q*16 + i*8;
        u16x8 v = {0,0,0,0,0,0,0,0};
        if(r0+r < NN) v = *(const u16x8*)(hb + (size_t)(r0+r)*HID + c0 + c);
        *(u16x8*)&ts[r][c] = v;
      }
    }
    __syncthreads();
    { int c = t>>2, q = t&3;
      unsigned short tmp[16];
      #pragma unroll
      for(int i=0;i<16;i++) tmp[i] = ts[q*16+i][c];
      unsigned short* dst = ht + (size_t)(c0+c)*KTP + r0 + q*16;
      *(u16x8*)(dst)   = *(u16x8*)&tmp[0];
      *(u16x8*)(dst+8) = *(u16x8*)&tmp[8];
    }
    __syncthreads();
  }
}

// ---------------- G = h^T h via MFMA on ht; only q in {0,1,3} (symmetry) ---
__global__ __launch_bounds__(256)
void gram_mfma(const unsigned short* __restrict__ ht, float* __restrict__ gp){
  const int qmap[3] = {0,1,3};
  int qi = blockIdx.x, q = qmap[qi], ch = blockIdx.y;
  __shared__ unsigned short as[128][72], bs[128][72];
  int r0 = (q>>1)*128, c0 = (q&1)*128;
  int t = threadIdx.x, w=t>>6, lane=t&63;
  int wr=w>>1, wc=w&1;
  f32x4 acc[4][4];
  #pragma unroll
  for(int i=0;i<4;i++)
    #pragma unroll
    for(int j=0;j<4;j++) acc[i][j] = (f32x4){0.f,0.f,0.f,0.f};
  size_t kbase = (size_t)ch*CHK;
  for(int k0=0;k0<CHK;k0+=64){
    { int r = t>>1, h2 = t&1;
      const unsigned short* srcA = ht + (size_t)(r0+r)*KTP + kbase + k0 + h2*32;
      const unsigned short* srcB = ht + (size_t)(c0+r)*KTP + kbase + k0 + h2*32;
      #pragma unroll
      for(int i=0;i<4;i++) *(u16x8*)&as[r][h2*32+i*8] = *(const u16x8*)(srcA + i*8);
      #pragma unroll
      for(int i=0;i<4;i++) *(u16x8*)&bs[r][h2*32+i*8] = *(const u16x8*)(srcB + i*8);
    }
    __syncthreads();
    #pragma unroll
    for(int ks=0;ks<2;ks++){
      i32x4 af[4], bfv[4];
      #pragma unroll
      for(int i=0;i<4;i++) af[i]  = *(const i32x4*)&as[wr*64 + i*16 + (lane&15)][ks*32 + (lane>>4)*8];
      #pragma unroll
      for(int j=0;j<4;j++) bfv[j] = *(const i32x4*)&bs[wc*64 + j*16 + (lane&15)][ks*32 + (lane>>4)*8];
      #pragma unroll
      for(int i=0;i<4;i++)
        #pragma unroll
        for(int j=0;j<4;j++) mfma16(acc[i][j], af[i], bfv[j]);
    }
    __syncthreads();
  }
  float* dst = gp + ((size_t)qi*NCH + ch)*16384;
  #pragma unroll
  for(int i=0;i<4;i++)
    #pragma unroll
    for(int j=0;j<4;j++)
      #pragma unroll
      for(int r=0;r<4;r++)
        dst[(wr*64+i*16+(lane>>4)*4+r)*128 + wc*64+j*16+(lane&15)] = acc[i][j][r];
}

// ---- merged: gram partial-reduce (+mirror) AND svec row-sums of ht --------
__global__ void gram_post(const float* __restrict__ gp, float* __restrict__ G,
                          const unsigned short* __restrict__ ht, float* __restrict__ svec){
  int b = blockIdx.x;
  if(b < 192){
    int qi = b>>6; int e = (b&63)*256 + threadIdx.x;
    const float* p = gp + (size_t)qi*NCH*16384 + e;
    float s=0.f;
    for(int c=0;c<NCH;c++) s += p[(size_t)c*16384];
    int i = e>>7, j = e&127;
    int r0 = (qi==2)?128:0, c0 = (qi==0)?0:128;
    G[(r0+i)*256 + c0+j] = s;
    if(qi==1) G[(c0+j)*256 + (r0+i)] = s;
  } else {
    int row = b - 192;
    const unsigned short* p = ht + (size_t)row*KTP;
    float s = 0.f;
    for(int i = threadIdx.x*8; i < KTP; i += 2048){
      u16x8 v = *(const u16x8*)(p + i);
      #pragma unroll
      for(int e=0;e<8;e++) s += bf2f(v[e]);
    }
    __shared__ float sh4[4];
    float tot = block_reduce(s, sh4);
    if(threadIdx.x==0) svec[row] = tot;
  }
}

// ---------------- gw_z = G @ W_z (z=0,1,2) fp32 ----------------------------
__global__ void gw_gemm3(const float* __restrict__ G, const float* __restrict__ Wq,
                         const float* __restrict__ Wk, const float* __restrict__ Wv,
                         float* __restrict__ gw){
  const float* B = blockIdx.z==0?Wq:(blockIdx.z==1?Wk:Wv);
  float* C = gw + (size_t)blockIdx.z*262144;
  __shared__ float As[64][33];
  __shared__ float Bs[32][64];
  int bm = blockIdx.x*64, bn = blockIdx.y*64;
  int t = threadIdx.x;
  int tn = t & 15, tm = t >> 4;
  float acc[4][4] = {};
  for(int k0=0;k0<HID;k0+=32){
    { int kk=t&31, rr=t>>5;
      #pragma unroll
      for(int p=0;p<8;p++){ int r=rr+p*8;
        As[r][kk] = G[(size_t)(bm+r)*HID + k0+kk]; } }
    { int nn=t&63, kr=t>>6;
      #pragma unroll
      for(int p=0;p<8;p++){ int k=kr+p*4;
        Bs[k][nn] = B[(size_t)(k0+k)*PJ + bn+nn]; } }
    __syncthreads();
    for(int k=0;k<32;k++){
      float a[4], b[4];
      #pragma unroll
      for(int i=0;i<4;i++) a[i]=As[tm*4+i][k];
      #pragma unroll
      for(int j=0;j<4;j++) b[j]=Bs[k][tn*4+j];
      #pragma unroll
      for(int i=0;i<4;i++)
        #pragma unroll
        for(int j=0;j<4;j++) acc[i][j] += a[i]*b[j];
    }
    __syncthreads();
  }
  #pragma unroll
  for(int i=0;i<4;i++)
    #pragma unroll
    for(int j=0;j<4;j++)
      C[(size_t)(bm+tm*4+i)*PJ + bn+tn*4+j] = acc[i][j];
}

// ---- merged: avec = W^T s (blocks 0..11) AND trace partials (12..139) -----
__global__ void wtr(const float* __restrict__ Wq, const float* __restrict__ Wk,
                    const float* __restrict__ Wv, const float* __restrict__ s,
                    const float* __restrict__ gw, float* __restrict__ avec,
                    float* __restrict__ trp){
  int b = blockIdx.x;
  if(b < 12){
    int z = b>>2, by = b&3;
    const float* Wsel = (z==0)?Wq:(z==1)?Wk:Wv;
    int col = by*256 + threadIdx.x;
    __shared__ float ss[256];
    ss[threadIdx.x]=s[threadIdx.x];
    __syncthreads();
    float acc=0.f;
    for(int i=0;i<256;i++) acc += Wsel[(size_t)i*PJ + col]*ss[i];
    avec[(size_t)z*1024 + col]=acc;
  } else {
    int b2 = b-12;
    int which = b2>>6, by = b2&63;
    const float* Wsel = which ? Wk : Wq;
    const float* GW = gw + (size_t)which*262144;
    int t=threadIdx.x;
    int base = by*4096 + t;
    float sm=0.f;
    #pragma unroll
    for(int i=0;i<16;i++){ int idx=base+i*256; sm += Wsel[idx]*GW[idx]; }
    __shared__ float sh4[4];
    float r = block_reduce(sm, sh4);
    if(t==0) trp[which*64 + by] = r;
  }
}

// ---------------- kvs (+ finalize_scalars at tile==16) ---------------------
__global__ void kvs_k(const float* __restrict__ Wk, const float* __restrict__ GWv,
                      const float* __restrict__ avec, const float* __restrict__ bk,
                      const float* __restrict__ bv, float* __restrict__ kvs,
                      const float* __restrict__ trp, const float* __restrict__ bq,
                      float* __restrict__ ksum, float* __restrict__ scal){
  int hh=blockIdx.x, tile=blockIdx.y;
  if(tile==16){
    if(hh!=0) return;
    __shared__ float sh4[4];
    int t=threadIdx.x;
    float pq = (t<64)? trp[t]    : 0.f;
    float pk = (t<64)? trp[64+t] : 0.f;
    float bqaq=0.f,bkak=0.f,bq2=0.f,bk2=0.f;
    #pragma unroll
    for(int p=0;p<4;p++){ int jn=t+p*256;
      float qv=bq[jn], kv=bk[jn];
      bqaq += qv*avec[jn]; bkak += kv*avec[1024+jn];
      bq2 += qv*qv; bk2 += kv*kv; }
    float tq = block_reduce(pq, sh4);
    float tk = block_reduce(pk, sh4);
    float s1 = block_reduce(bqaq, sh4);
    float s2 = block_reduce(bkak, sh4);
    float s3 = block_reduce(bq2, sh4);
    float s4 = block_reduce(bk2, sh4);
    if(t==0){
      float q2 = tq + 2.f*s1 + FN*s3;
      float k2 = tk + 2.f*s2 + FN*s4;
      scal[0] = rsqrtf(q2)*rsqrtf(k2);
    }
    #pragma unroll
    for(int p=0;p<4;p++){ int jn=t+p*256; ksum[jn] = avec[1024+jn] + FN*bk[jn]; }
    return;
  }
  int m0=(tile>>2)*64, d0=(tile&3)*64;
  __shared__ float As[32][64], Bs[32][64];
  int t=threadIdx.x, tn=t&15, tm=t>>4;
  float acc[4][4]={};
  for(int k0=0;k0<256;k0+=32){
    int kr=t>>6, cc=t&63;
    #pragma unroll
    for(int p=0;p<8;p++){
      int k=kr+p*4;
      As[k][cc] = Wk [(size_t)(k0+k)*PJ + hh*256 + m0+cc];
      Bs[k][cc] = GWv[(size_t)(k0+k)*PJ + hh*256 + d0+cc];
    }
    __syncthreads();
    for(int k=0;k<32;k++){
      float a[4], b[4];
      #pragma unroll
      for(int i=0;i<4;i++) a[i]=As[k][tm*4+i];
      #pragma unroll
      for(int j=0;j<4;j++) b[j]=Bs[k][tn*4+j];
      #pragma unroll
      for(int i=0;i<4;i++)
        #pragma unroll
        for(int j=0;j<4;j++) acc[i][j] += a[i]*b[j];
    }
    __syncthreads();
  }
  const float* ak = avec+1024; const float* av = avec+2048;
  #pragma unroll
  for(int i=0;i<4;i++)
    #pragma unroll
    for(int j=0;j<4;j++){
      int m=m0+tm*4+i, d=d0+tn*4+j;
      float akm=ak[hh*256+m], bkm=bk[hh*256+m];
      float avd=av[hh*256+d], bvd=bv[hh*256+d];
      kvs[(size_t)hh*65536 + m*256 + d] = acc[i][j] + akm*bvd + bkm*avd + FN*bkm*bvd;
    }
}

// -------- U = scale*Wq@kvs + N*Wv, written TILED bf16 (R10 Ut2 layout) -----
__global__ void u_gemm(const float* __restrict__ Wq, const float* __restrict__ kvs,
                       const float* __restrict__ Wv, const float* __restrict__ scal,
                       unsigned short* __restrict__ Ut2){
  int hh=blockIdx.x, tile=blockIdx.y;
  int i0=(tile>>2)*64, d0=(tile&3)*64;
  __shared__ float As[64][33]; __shared__ float Bs[32][64];
  int t=threadIdx.x, tn=t&15, tm=t>>4;
  float acc[4][4]={};
  for(int k0=0;k0<256;k0+=32){
    { int kk=t&31, rr=t>>5;
      #pragma unroll
      for(int p=0;p<8;p++){ int r=rr+p*8;
        As[r][kk] = Wq[(size_t)(i0+r)*PJ + hh*256 + k0+kk]; } }
    { int kr=t>>6, cc=t&63;
      #pragma unroll
      for(int p=0;p<8;p++){ int k=kr+p*4;
        Bs[k][cc] = kvs[(size_t)hh*65536 + (k0+k)*256 + d0+cc]; } }
    __syncthreads();
    for(int k=0;k<32;k++){
      float a[4], b[4];
      #pragma unroll
      for(int i=0;i<4;i++) a[i]=As[tm*4+i][k];
      #pragma unroll
      for(int j=0;j<4;j++) b[j]=Bs[k][tn*4+j];
      #pragma unroll
      for(int i=0;i<4;i++)
        #pragma unroll
        for(int j=0;j<4;j++) acc[i][j] += a[i]*b[j];
    }
    __syncthreads();
  }
  float sc = scal[0];
  #pragma unroll
  for(int i=0;i<4;i++)
    #pragma unroll
    for(int j=0;j<4;j++){
      int ii=i0+tm*4+i, d=d0+tn*4+j;
      float val = sc*acc[i][j] + FN*Wv[(size_t)ii*PJ + hh*256 + d];
      Ut2[((size_t)(d>>6)*4 + (ii>>6))*16384 + ((size_t)hh*64 + (d&63))*64 + (ii&63)] = f2bf(val);
    }
}

// ---------------- per-head vectors -----------------------------------------
__global__ void head_vecs(const float* __restrict__ Wq, const float* __restrict__ bq,
                          const float* __restrict__ bv, const float* __restrict__ kvs,
                          const float* __restrict__ ksum, const float* __restrict__ scal,
                          float* __restrict__ uvec, float* __restrict__ wvec,
                          float* __restrict__ cvec){
  int hh=blockIdx.x, t=threadIdx.x;
  float scale=scal[0];
  __shared__ float bqs[256], kss[256];
  __shared__ float sh4[4];
  bqs[t]=bq[hh*256+t]; kss[t]=ksum[hh*256+t];
  __syncthreads();
  float su=0.f;
  for(int m=0;m<256;m++) su += bqs[m]*kvs[(size_t)hh*65536 + m*256 + t];
  uvec[hh*256+t] = scale*su + FN*bv[hh*256+t];
  float sw=0.f;
  for(int m=0;m<256;m++) sw += Wq[(size_t)t*PJ + hh*256 + m]*kss[m];
  wvec[hh*256+t] = scale*sw;
  float pc = bqs[t]*kss[t];
  float total = block_reduce(pc, sh4);
  if(t==0) cvec[hh] = scale*total + FN;
}

// ------- denom (reciprocal), bf16 h input; 32 rows/block --------------------
__global__ void denom_k(const unsigned short* __restrict__ hb, const float* __restrict__ wvec,
                        const float* __restrict__ cvec, float* __restrict__ denom, int M){
  __shared__ float wvl[1024];
  for(int i=threadIdx.x;i<1024;i+=256) wvl[i]=wvec[i];
  __syncthreads();
  int lane=threadIdx.x&63, wv=threadIdx.x>>6;
  int base = blockIdx.x*32 + wv*8;
  for(int rr=0; rr<8; rr++){
    int row = base + rr;
    if(row>=M) break;
    ushort4 hv = *(const ushort4*)(hb + (size_t)row*HID + lane*4);
    float h0=bf2f(hv.x), h1=bf2f(hv.y), h2=bf2f(hv.z), h3=bf2f(hv.w);
    float p[4];
    #pragma unroll
    for(int hh=0;hh<4;hh++){
      const float* wl = wvl + hh*256 + lane*4;
      p[hh] = h0*wl[0] + h1*wl[1] + h2*wl[2] + h3*wl[3];
    }
    #pragma unroll
    for(int hh=0;hh<4;hh++) p[hh]=wave_reduce(p[hh]);
    if(lane==0){
      #pragma unroll
      for(int hh=0;hh<4;hh++) denom[(size_t)row*4+hh] = 1.0f/(p[hh]+cvec[hh]);
    }
  }
}

// ---------------- attn (R10-proven): BM=128, strips of 64, 8 waves 4x2 -----
__global__ __launch_bounds__(512,4)
void attn_mfma(const unsigned short* __restrict__ hb, const unsigned short* __restrict__ Ut2,
               const float* __restrict__ uvec, const float* __restrict__ rden,
               unsigned short* __restrict__ outp){
  __shared__ __align__(16) unsigned char smem[38912];
  unsigned short (*bs)[72] = (unsigned short(*)[72])smem;   // 256 x 72
  float (*red)[64] = (float(*)[64])smem;                    // overlay after loop
  float (*rsh)[4]  = (float(*)[4])(smem + 36864);           // 128 x 4
  int bm = blockIdx.x*128;
  int st = blockIdx.y;
  int t = threadIdx.x, w = t>>6, lane = t&63;
  int wr = w>>1, wc = w&1;
  int nst = t>>1, koff = (t&1)*32;

  f32x16 acc[4];
  #pragma unroll
  for(int j=0;j<4;j++)
    #pragma unroll
    for(int e=0;e<16;e++) acc[j][e]=0.f;

  { int r = t>>2, h2 = t&3;
    rsh[r][h2] = (bm+r<NN) ? rden[(size_t)(bm+r)*4+h2] : 1.0f; }

  const unsigned short* tb0 = Ut2 + (size_t)st*4*16384;
  u16x8 breg[4];
  #pragma unroll
  for(int i=0;i<4;i++) breg[i] = *(const u16x8*)(tb0 + (size_t)t*32 + i*8);

  int arow = bm + wr*32 + (lane&31); if(arow >= NN) arow = NN-1;
  const unsigned short* ap = hb + (size_t)arow*HID + (lane>>5)*8;

  #pragma unroll
  for(int kb=0;kb<4;kb++){
    __syncthreads();
    #pragma unroll
    for(int i=0;i<4;i++) *(u16x8*)&bs[nst][koff + i*8] = breg[i];
    __syncthreads();
    if(kb<3){
      const unsigned short* tn2 = Ut2 + ((size_t)st*4 + kb+1)*16384;
      #pragma unroll
      for(int i=0;i<4;i++) breg[i] = *(const u16x8*)(tn2 + (size_t)t*32 + i*8);
    }
    i32x4 a[4];
    #pragma unroll
    for(int ks=0;ks<4;ks++) a[ks] = *(const i32x4*)(ap + kb*64 + ks*16);
    #pragma unroll
    for(int ks=0;ks<4;ks++){
      int kc = ks*16 + (lane>>5)*8;
      #pragma unroll
      for(int j=0;j<4;j++){
        i32x4 b = *(const i32x4*)&bs[wc*128 + j*32 + (lane&31)][kc];
        mfma32(acc[j], a[ks], b);
      }
    }
  }
  float uv[4];
  #pragma unroll
  for(int j=0;j<4;j++)
    uv[j] = uvec[(wc*2 + (j>>1))*256 + st*64 + (j&1)*32 + (lane&31)];
  __syncthreads();
  if(wc==1){
    #pragma unroll
    for(int r=0;r<16;r++){
      int row = wr*32 + (r&3) + ((r>>2)<<3) + ((lane>>5)<<2);
      float d0 = rsh[row][2], d1 = rsh[row][3];
      red[row][lane&31]      = (acc[0][r]+uv[0])*d0 + (acc[2][r]+uv[2])*d1;
      red[row][32+(lane&31)] = (acc[1][r]+uv[1])*d0 + (acc[3][r]+uv[3])*d1;
    }
  }
  __syncthreads();
  if(wc==0){
    #pragma unroll
    for(int r=0;r<16;r++){
      int row = wr*32 + (r&3) + ((r>>2)<<3) + ((lane>>5)<<2);
      int gr = bm + row;
      if(gr < NN){
        float d0 = rsh[row][0], d1 = rsh[row][1];
        float v0 = ((acc[0][r]+uv[0])*d0 + (acc[2][r]+uv[2])*d1 + red[row][lane&31])      * 0.25f;
        float v1 = ((acc[1][r]+uv[1])*d0 + (acc[3][r]+uv[3])*d1 + red[row][32+(lane&31)]) * 0.25f;
        const unsigned short* hres = hb + (size_t)gr*HID + st*64;
        unsigned short* dst = outp + (size_t)gr*HID + st*64;
        dst[lane&31]      = f2bf((v0 + bf2f(hres[lane&31])) * 0.5f);
        dst[32+(lane&31)] = f2bf((v1 + bf2f(hres[32+(lane&31)])) * 0.5f);
      }
    }
  }
}

extern "C" void kernel_launch(void* const* d_in, const int* in_sizes, int n_in,
                              void* d_out, int out_size, void* d_ws, size_t ws_size,
                              hipStream_t stream){
  const float* x    = (const float*)d_in[0];
  const float* fc_w = (const float*)d_in[1];
  const float* fc_b = (const float*)d_in[2];
  const float* ln0g = (const float*)d_in[3];
  const float* ln0b = (const float*)d_in[4];
  float* out = (float*)d_out;

  float* W = (float*)d_ws;
  size_t o=0;
  unsigned short* hpre = (unsigned short*)(W+o); o+=(size_t)NN*HID/2;   // bf16 pre-LN
  unsigned short* hb   = (unsigned short*)(W+o); o+=(size_t)NN*HID/2;
  unsigned short* ht   = (unsigned short*)(W+o); o+=(size_t)HID*KTP/2;
  unsigned short* FWT2 = (unsigned short*)(W+o); o+=(size_t)8*16384/2 + 8;
  unsigned short* Ut2  = (unsigned short*)(W+o); o+=(size_t)16*16384/2 + 8;
  float* gramp= W+o; o+=(size_t)3*NCH*16384;
  float* G    = W+o; o+=65536;
  float* gw   = W+o; o+=3*262144;
  float* svec = W+o; o+=256;
  float* avec = W+o; o+=3072;
  float* trp  = W+o; o+=128;
  float* scal = W+o; o+=16;
  float* ksum = W+o; o+=1024;
  float* kvs  = W+o; o+=262144;
  float* uvec = W+o; o+=1024;
  float* wvec = W+o; o+=1024;
  float* cvec = W+o; o+=8;
  float* denB = W+o; o+=(size_t)NN*4;
  (void)ws_size; (void)in_sizes; (void)n_in; (void)out_size;

  dim3 blk(256);
  wconv<<<dim3(512),blk,0,stream>>>(fc_w, FWT2);
  ffn_gemm<<<dim3(391),dim3(512),0,stream>>>(x, FWT2, fc_b, ln0g, ln0b, hb);

  for(int L=0; L<2; L++){
    const float* wq = (const float*)d_in[5+L*8+0];
    const float* bq = (const float*)d_in[5+L*8+1];
    const float* wk = (const float*)d_in[5+L*8+2];
    const float* bk = (const float*)d_in[5+L*8+3];
    const float* wv = (const float*)d_in[5+L*8+4];
    const float* bv = (const float*)d_in[5+L*8+5];
    const float* lng= (const float*)d_in[5+L*8+6];
    const float* lnb= (const float*)d_in[5+L*8+7];

    transpose_h<<<dim3(784),blk,0,stream>>>(hb, ht);
    gram_mfma<<<dim3(3,NCH),blk,0,stream>>>(ht, gramp);
    gram_post<<<dim3(448),blk,0,stream>>>(gramp, G, ht, svec);
    gw_gemm3<<<dim3(4,16,3),blk,0,stream>>>(G, wq, wk, wv, gw);
    wtr<<<dim3(140),blk,0,stream>>>(wq, wk, wv, svec, gw, avec, trp);
    kvs_k<<<dim3(4,17),blk,0,stream>>>(wk, gw+2*262144, avec, bk, bv, kvs,
                                       trp, bq, ksum, scal);
    u_gemm<<<dim3(4,16),blk,0,stream>>>(wq, kvs, wv, scal, Ut2);
    head_vecs<<<dim3(4),blk,0,stream>>>(wq,bq,bv,kvs,ksum,scal,uvec,wvec,cvec);
    denom_k<<<dim3(1563),blk,0,stream>>>(hb, wvec, cvec, denB, NN);
    attn_mfma<<<dim3(391,4),dim3(512),0,stream>>>(hb, Ut2, uvec, denB, hpre);
    ln_relu2b<<<dim3(1563),blk,0,stream>>>(hpre, lng, lnb,
                                           L ? (unsigned short*)nullptr : hb,
                                           L ? out : (float*)nullptr, NN);
  }
}

// Round 16
// 476.511 us; speedup vs baseline: 1.0162x; 1.0162x over previous
//
#include <hip/hip_runtime.h>

#define NN    50000
#define IN_CH 512
#define HID   256
#define PJ    1024
#define FN    50000.0f
#define KTP   50176          // padded node-dim for ht (784*64)
#define NCH   98
#define CHK   512

typedef __attribute__((ext_vector_type(4)))  float f32x4;
typedef __attribute__((ext_vector_type(16))) float f32x16;
typedef __attribute__((ext_vector_type(4)))  int   i32x4;
typedef __attribute__((ext_vector_type(8)))  unsigned short u16x8;

__device__ inline void mfma16(f32x4& c, i32x4 a, i32x4 b){
  asm("v_mfma_f32_16x16x32_bf16 %0, %1, %2, %0" : "+v"(c) : "v"(a), "v"(b));
}
__device__ inline void mfma32(f32x16& c, i32x4 a, i32x4 b){
  asm("v_mfma_f32_32x32x16_bf16 %0, %1, %2, %0" : "+v"(c) : "v"(a), "v"(b));
}

__device__ inline unsigned short f2bf(float f){
  unsigned int u = __builtin_bit_cast(unsigned int, f);
  unsigned int r = (u + 0x7fffu + ((u >> 16) & 1u)) >> 16;
  return (unsigned short)r;
}
__device__ inline float bf2f(unsigned short u){
  unsigned int x = ((unsigned int)u) << 16;
  return __builtin_bit_cast(float, x);
}

__device__ inline float wave_reduce(float v){
  #pragma unroll
  for(int o=32;o>0;o>>=1) v += __shfl_down(v,o,64);
  return v;
}
__device__ inline float block_reduce(float v, float* sh4){
  v = wave_reduce(v);
  int lane = threadIdx.x & 63, wv = threadIdx.x >> 6;
  if(lane==0) sh4[wv] = v;
  __syncthreads();
  float r = sh4[0]+sh4[1]+sh4[2]+sh4[3];
  __syncthreads();
  return r;
}

// ---- fc_w [512][256] fp32 -> FWT2 tiled bf16 [kb=8][256 n][64 k] ----------
__global__ void wconv(const float* __restrict__ w, unsigned short* __restrict__ wt){
  int idx = blockIdx.x*256 + threadIdx.x;
  if(idx >= IN_CH*HID) return;
  int k = idx >> 8, n = idx & 255;
  wt[((size_t)(k>>6)*256 + n)*64 + (k&63)] = f2bf(w[idx]);
}

// ---------------- FFN + fused LN + ReLU -> hb bf16 (R7/R10-proven) ---------
__global__ __launch_bounds__(512)
void ffn_gemm(const float* __restrict__ X, const unsigned short* __restrict__ FWT2,
              const float* __restrict__ bias, const float* __restrict__ g,
              const float* __restrict__ b2, unsigned short* __restrict__ hbo){
  __shared__ __align__(16) unsigned char smem[55296];
  unsigned short (*as)[72] = (unsigned short(*)[72])smem;            // 128x72
  unsigned short (*bs)[72] = (unsigned short(*)[72])(smem + 18432);  // 256x72
  int t = threadIdx.x;
  int bm = blockIdx.x*128;
  int w = t>>6, lane = t&63;
  int wr = w>>2, wc = w&3;
  f32x4 acc[4][4];
  #pragma unroll
  for(int i=0;i<4;i++)
    #pragma unroll
    for(int j=0;j<4;j++) acc[i][j] = (f32x4){0.f,0.f,0.f,0.f};

  int ar = t>>2, aq = t&3;
  bool aok = (bm+ar) < NN;
  const float* xsrc = X + (size_t)(bm+ar)*IN_CH + aq*16;
  ushort4 aregs[4];
  u16x8 bregs[4];
  #pragma unroll
  for(int i=0;i<4;i++){
    float4 v = aok ? *(const float4*)(xsrc + i*4) : make_float4(0.f,0.f,0.f,0.f);
    ushort4 u; u.x=f2bf(v.x); u.y=f2bf(v.y); u.z=f2bf(v.z); u.w=f2bf(v.w);
    aregs[i]=u;
  }
  #pragma unroll
  for(int i=0;i<4;i++) bregs[i] = *(const u16x8*)(FWT2 + (size_t)t*32 + i*8);

  for(int kb=0;kb<8;kb++){
    __syncthreads();
    #pragma unroll
    for(int i=0;i<4;i++) *(ushort4*)&as[ar][aq*16 + i*4] = aregs[i];
    { int n = t>>1, q = t&1;
      #pragma unroll
      for(int i=0;i<4;i++) *(u16x8*)&bs[n][q*32 + i*8] = bregs[i];
    }
    __syncthreads();
    if(kb<7){
      const float* xs2 = xsrc + (kb+1)*64;
      #pragma unroll
      for(int i=0;i<4;i++){
        float4 v = aok ? *(const float4*)(xs2 + i*4) : make_float4(0.f,0.f,0.f,0.f);
        ushort4 u; u.x=f2bf(v.x); u.y=f2bf(v.y); u.z=f2bf(v.z); u.w=f2bf(v.w);
        aregs[i]=u;
      }
      const unsigned short* bsrc = FWT2 + (size_t)(kb+1)*16384 + (size_t)t*32;
      #pragma unroll
      for(int i=0;i<4;i++) bregs[i] = *(const u16x8*)(bsrc + i*8);
    }
    #pragma unroll
    for(int ks=0;ks<2;ks++){
      i32x4 af[4], bfv[4];
      #pragma unroll
      for(int i=0;i<4;i++) af[i]  = *(const i32x4*)&as[wr*64 + i*16 + (lane&15)][ks*32 + (lane>>4)*8];
      #pragma unroll
      for(int j=0;j<4;j++) bfv[j] = *(const i32x4*)&bs[wc*64 + j*16 + (lane&15)][ks*32 + (lane>>4)*8];
      #pragma unroll
      for(int i=0;i<4;i++)
        #pragma unroll
        for(int j=0;j<4;j++) mfma16(acc[i][j], af[i], bfv[j]);
    }
  }
  __syncthreads();
  int cb = wc*64;
  #pragma unroll
  for(int j=0;j<4;j++){
    float bb = bias[cb + j*16 + (lane&15)];
    #pragma unroll
    for(int i=0;i<4;i++)
      #pragma unroll
      for(int r=0;r<4;r++) acc[i][j][r] += bb;
  }
  float (*lnp)[4][2] = (float(*)[4][2])smem;
  float (*lnstat)[2] = (float(*)[2])(smem + 4096);
  #pragma unroll
  for(int i=0;i<4;i++)
    #pragma unroll
    for(int r=0;r<4;r++){
      float s=0.f, q=0.f;
      #pragma unroll
      for(int j=0;j<4;j++){ float a=acc[i][j][r]; s+=a; q+=a*a; }
      #pragma unroll
      for(int m=1;m<16;m<<=1){ s += __shfl_xor(s,m,64); q += __shfl_xor(q,m,64); }
      if((lane&15)==0){
        int row = wr*64 + i*16 + (lane>>4)*4 + r;
        lnp[row][wc][0]=s; lnp[row][wc][1]=q;
      }
    }
  __syncthreads();
  if(t<128){
    float s=0.f,q=0.f;
    #pragma unroll
    for(int c=0;c<4;c++){ s+=lnp[t][c][0]; q+=lnp[t][c][1]; }
    float mu = s*(1.f/HID);
    float var = q*(1.f/HID) - mu*mu;
    lnstat[t][0]=mu; lnstat[t][1]=rsqrtf(var+1e-5f);
  }
  __syncthreads();
  #pragma unroll
  for(int j=0;j<4;j++){
    int col = cb + j*16 + (lane&15);
    float gg = g[col], bb = b2[col];
    #pragma unroll
    for(int i=0;i<4;i++)
      #pragma unroll
      for(int r=0;r<4;r++){
        int row = wr*64 + i*16 + (lane>>4)*4 + r;
        int grow = bm + row;
        if(grow<NN){
          float y = fmaxf((acc[i][j][r]-lnstat[row][0])*lnstat[row][1]*gg + bb, 0.f);
          hbo[(size_t)grow*HID + col] = f2bf(y);
        }
      }
  }
}

// ---------------- LN+ReLU (post-attn): bf16 in -> bf16 and/or fp32 out -----
__global__ void ln_relu2b(const unsigned short* __restrict__ in, const float* __restrict__ g,
                          const float* __restrict__ b, unsigned short* __restrict__ outb,
                          float* __restrict__ outf, int M){
  int lane = threadIdx.x & 63, wv = threadIdx.x >> 6;
  int row = blockIdx.x*4 + wv;
  if(row>=M) return;
  const unsigned short* rp = in + (size_t)row*HID;
  ushort4 hv = *(const ushort4*)(rp + lane*4);
  float v[4] = {bf2f(hv.x), bf2f(hv.y), bf2f(hv.z), bf2f(hv.w)};
  float sum = v[0]+v[1]+v[2]+v[3];
  float sq  = v[0]*v[0]+v[1]*v[1]+v[2]*v[2]+v[3]*v[3];
  sum = wave_reduce(sum); sq = wave_reduce(sq);
  sum = __shfl(sum,0,64); sq = __shfl(sq,0,64);
  float mu = sum*(1.f/HID);
  float var = sq*(1.f/HID) - mu*mu;
  float rs = rsqrtf(var + 1e-5f);
  float y[4];
  #pragma unroll
  for(int j=0;j<4;j++){ int c=lane*4+j;
    y[j] = fmaxf((v[j]-mu)*rs*g[c] + b[c], 0.f); }
  if(outb){
    ushort4 u; u.x=f2bf(y[0]); u.y=f2bf(y[1]); u.z=f2bf(y[2]); u.w=f2bf(y[3]);
    *(ushort4*)(outb + (size_t)row*HID + lane*4) = u;
  }
  if(outf){
    float4 f; f.x=y[0]; f.y=y[1]; f.z=y[2]; f.w=y[3];
    *(float4*)(outf + (size_t)row*HID + lane*4) = f;
  }
}

// ---------------- hb [NN][256] bf16 -> ht [256][KTP] bf16 (zero-padded) ----
__global__ __launch_bounds__(256)
void transpose_h(const unsigned short* __restrict__ hb, unsigned short* __restrict__ ht){
  __shared__ unsigned short ts[64][72];
  int r0 = blockIdx.x*64, c0 = blockIdx.y*64;
  int t = threadIdx.x;
  { int r = t&63, q = t>>6;
    #pragma unroll
    for(int i=0;i<2;i++){
      int c = q*16 + i*8;
      u16x8 v = {0,0,0,0,0,0,0,0};
      if(r0+r < NN) v = *(const u16x8*)(hb + (size_t)(r0+r)*HID + c0 + c);
      *(u16x8*)&ts[r][c] = v;
    }
  }
  __syncthreads();
  { int c = t>>2, q = t&3;
    unsigned short tmp[16];
    #pragma unroll
    for(int i=0;i<16;i++) tmp[i] = ts[q*16+i][c];
    unsigned short* dst = ht + (size_t)(c0+c)*KTP + r0 + q*16;
    *(u16x8*)(dst)   = *(u16x8*)&tmp[0];
    *(u16x8*)(dst+8) = *(u16x8*)&tmp[8];
  }
}

// ---------------- G = h^T h via MFMA on ht; only q in {0,1,3} (symmetry) ---
__global__ __launch_bounds__(256)
void gram_mfma(const unsigned short* __restrict__ ht, float* __restrict__ gp){
  const int qmap[3] = {0,1,3};
  int qi = blockIdx.x, q = qmap[qi], ch = blockIdx.y;
  __shared__ unsigned short as[128][72], bs[128][72];
  int r0 = (q>>1)*128, c0 = (q&1)*128;
  int t = threadIdx.x, w=t>>6, lane=t&63;
  int wr=w>>1, wc=w&1;
  f32x4 acc[4][4];
  #pragma unroll
  for(int i=0;i<4;i++)
    #pragma unroll
    for(int j=0;j<4;j++) acc[i][j] = (f32x4){0.f,0.f,0.f,0.f};
  size_t kbase = (size_t)ch*CHK;
  for(int k0=0;k0<CHK;k0+=64){
    { int r = t>>1, h2 = t&1;
      const unsigned short* srcA = ht + (size_t)(r0+r)*KTP + kbase + k0 + h2*32;
      const unsigned short* srcB = ht + (size_t)(c0+r)*KTP + kbase + k0 + h2*32;
      #pragma unroll
      for(int i=0;i<4;i++) *(u16x8*)&as[r][h2*32+i*8] = *(const u16x8*)(srcA + i*8);
      #pragma unroll
      for(int i=0;i<4;i++) *(u16x8*)&bs[r][h2*32+i*8] = *(const u16x8*)(srcB + i*8);
    }
    __syncthreads();
    #pragma unroll
    for(int ks=0;ks<2;ks++){
      i32x4 af[4], bfv[4];
      #pragma unroll
      for(int i=0;i<4;i++) af[i]  = *(const i32x4*)&as[wr*64 + i*16 + (lane&15)][ks*32 + (lane>>4)*8];
      #pragma unroll
      for(int j=0;j<4;j++) bfv[j] = *(const i32x4*)&bs[wc*64 + j*16 + (lane&15)][ks*32 + (lane>>4)*8];
      #pragma unroll
      for(int i=0;i<4;i++)
        #pragma unroll
        for(int j=0;j<4;j++) mfma16(acc[i][j], af[i], bfv[j]);
    }
    __syncthreads();
  }
  float* dst = gp + ((size_t)qi*NCH + ch)*16384;
  #pragma unroll
  for(int i=0;i<4;i++)
    #pragma unroll
    for(int j=0;j<4;j++)
      #pragma unroll
      for(int r=0;r<4;r++)
        dst[(wr*64+i*16+(lane>>4)*4+r)*128 + wc*64+j*16+(lane&15)] = acc[i][j][r];
}

// ---- merged: gram partial-reduce (+mirror) AND svec row-sums of ht --------
__global__ void gram_post(const float* __restrict__ gp, float* __restrict__ G,
                          const unsigned short* __restrict__ ht, float* __restrict__ svec){
  int b = blockIdx.x;
  if(b < 192){
    int qi = b>>6; int e = (b&63)*256 + threadIdx.x;
    const float* p = gp + (size_t)qi*NCH*16384 + e;
    float s=0.f;
    for(int c=0;c<NCH;c++) s += p[(size_t)c*16384];
    int i = e>>7, j = e&127;
    int r0 = (qi==2)?128:0, c0 = (qi==0)?0:128;
    G[(r0+i)*256 + c0+j] = s;
    if(qi==1) G[(c0+j)*256 + (r0+i)] = s;
  } else {
    int row = b - 192;
    const unsigned short* p = ht + (size_t)row*KTP;
    float s = 0.f;
    for(int i = threadIdx.x*8; i < KTP; i += 2048){
      u16x8 v = *(const u16x8*)(p + i);
      #pragma unroll
      for(int e=0;e<8;e++) s += bf2f(v[e]);
    }
    __shared__ float sh4[4];
    float tot = block_reduce(s, sh4);
    if(threadIdx.x==0) svec[row] = tot;
  }
}

// ---------------- gw_z = G @ W_z (z=0,1,2) fp32 ----------------------------
__global__ void gw_gemm3(const float* __restrict__ G, const float* __restrict__ Wq,
                         const float* __restrict__ Wk, const float* __restrict__ Wv,
                         float* __restrict__ gw){
  const float* B = blockIdx.z==0?Wq:(blockIdx.z==1?Wk:Wv);
  float* C = gw + (size_t)blockIdx.z*262144;
  __shared__ float As[64][33];
  __shared__ float Bs[32][64];
  int bm = blockIdx.x*64, bn = blockIdx.y*64;
  int t = threadIdx.x;
  int tn = t & 15, tm = t >> 4;
  float acc[4][4] = {};
  for(int k0=0;k0<HID;k0+=32){
    { int kk=t&31, rr=t>>5;
      #pragma unroll
      for(int p=0;p<8;p++){ int r=rr+p*8;
        As[r][kk] = G[(size_t)(bm+r)*HID + k0+kk]; } }
    { int nn=t&63, kr=t>>6;
      #pragma unroll
      for(int p=0;p<8;p++){ int k=kr+p*4;
        Bs[k][nn] = B[(size_t)(k0+k)*PJ + bn+nn]; } }
    __syncthreads();
    for(int k=0;k<32;k++){
      float a[4], b[4];
      #pragma unroll
      for(int i=0;i<4;i++) a[i]=As[tm*4+i][k];
      #pragma unroll
      for(int j=0;j<4;j++) b[j]=Bs[k][tn*4+j];
      #pragma unroll
      for(int i=0;i<4;i++)
        #pragma unroll
        for(int j=0;j<4;j++) acc[i][j] += a[i]*b[j];
    }
    __syncthreads();
  }
  #pragma unroll
  for(int i=0;i<4;i++)
    #pragma unroll
    for(int j=0;j<4;j++)
      C[(size_t)(bm+tm*4+i)*PJ + bn+tn*4+j] = acc[i][j];
}

// ---- merged: avec = W^T s (blocks 0..11) AND trace partials (12..139) -----
__global__ void wtr(const float* __restrict__ Wq, const float* __restrict__ Wk,
                    const float* __restrict__ Wv, const float* __restrict__ s,
                    const float* __restrict__ gw, float* __restrict__ avec,
                    float* __restrict__ trp){
  int b = blockIdx.x;
  if(b < 12){
    int z = b>>2, by = b&3;
    const float* Wsel = (z==0)?Wq:(z==1)?Wk:Wv;
    int col = by*256 + threadIdx.x;
    __shared__ float ss[256];
    ss[threadIdx.x]=s[threadIdx.x];
    __syncthreads();
    float acc=0.f;
    for(int i=0;i<256;i++) acc += Wsel[(size_t)i*PJ + col]*ss[i];
    avec[(size_t)z*1024 + col]=acc;
  } else {
    int b2 = b-12;
    int which = b2>>6, by = b2&63;
    const float* Wsel = which ? Wk : Wq;
    const float* GW = gw + (size_t)which*262144;
    int t=threadIdx.x;
    int base = by*4096 + t;
    float sm=0.f;
    #pragma unroll
    for(int i=0;i<16;i++){ int idx=base+i*256; sm += Wsel[idx]*GW[idx]; }
    __shared__ float sh4[4];
    float r = block_reduce(sm, sh4);
    if(t==0) trp[which*64 + by] = r;
  }
}

// ---------------- kvs (+ finalize_scalars at tile==16) ---------------------
__global__ void kvs_k(const float* __restrict__ Wk, const float* __restrict__ GWv,
                      const float* __restrict__ avec, const float* __restrict__ bk,
                      const float* __restrict__ bv, float* __restrict__ kvs,
                      const float* __restrict__ trp, const float* __restrict__ bq,
                      float* __restrict__ ksum, float* __restrict__ scal){
  int hh=blockIdx.x, tile=blockIdx.y;
  if(tile==16){
    if(hh!=0) return;
    __shared__ float sh4[4];
    int t=threadIdx.x;
    float pq = (t<64)? trp[t]    : 0.f;
    float pk = (t<64)? trp[64+t] : 0.f;
    float bqaq=0.f,bkak=0.f,bq2=0.f,bk2=0.f;
    #pragma unroll
    for(int p=0;p<4;p++){ int jn=t+p*256;
      float qv=bq[jn], kv=bk[jn];
      bqaq += qv*avec[jn]; bkak += kv*avec[1024+jn];
      bq2 += qv*qv; bk2 += kv*kv; }
    float tq = block_reduce(pq, sh4);
    float tk = block_reduce(pk, sh4);
    float s1 = block_reduce(bqaq, sh4);
    float s2 = block_reduce(bkak, sh4);
    float s3 = block_reduce(bq2, sh4);
    float s4 = block_reduce(bk2, sh4);
    if(t==0){
      float q2 = tq + 2.f*s1 + FN*s3;
      float k2 = tk + 2.f*s2 + FN*s4;
      scal[0] = rsqrtf(q2)*rsqrtf(k2);
    }
    #pragma unroll
    for(int p=0;p<4;p++){ int jn=t+p*256; ksum[jn] = avec[1024+jn] + FN*bk[jn]; }
    return;
  }
  int m0=(tile>>2)*64, d0=(tile&3)*64;
  __shared__ float As[32][64], Bs[32][64];
  int t=threadIdx.x, tn=t&15, tm=t>>4;
  float acc[4][4]={};
  for(int k0=0;k0<256;k0+=32){
    int kr=t>>6, cc=t&63;
    #pragma unroll
    for(int p=0;p<8;p++){
      int k=kr+p*4;
      As[k][cc] = Wk [(size_t)(k0+k)*PJ + hh*256 + m0+cc];
      Bs[k][cc] = GWv[(size_t)(k0+k)*PJ + hh*256 + d0+cc];
    }
    __syncthreads();
    for(int k=0;k<32;k++){
      float a[4], b[4];
      #pragma unroll
      for(int i=0;i<4;i++) a[i]=As[k][tm*4+i];
      #pragma unroll
      for(int j=0;j<4;j++) b[j]=Bs[k][tn*4+j];
      #pragma unroll
      for(int i=0;i<4;i++)
        #pragma unroll
        for(int j=0;j<4;j++) acc[i][j] += a[i]*b[j];
    }
    __syncthreads();
  }
  const float* ak = avec+1024; const float* av = avec+2048;
  #pragma unroll
  for(int i=0;i<4;i++)
    #pragma unroll
    for(int j=0;j<4;j++){
      int m=m0+tm*4+i, d=d0+tn*4+j;
      float akm=ak[hh*256+m], bkm=bk[hh*256+m];
      float avd=av[hh*256+d], bvd=bv[hh*256+d];
      kvs[(size_t)hh*65536 + m*256 + d] = acc[i][j] + akm*bvd + bkm*avd + FN*bkm*bvd;
    }
}

// -------- U = scale*Wq@kvs + N*Wv, written TILED bf16 (R10 Ut2 layout) -----
__global__ void u_gemm(const float* __restrict__ Wq, const float* __restrict__ kvs,
                       const float* __restrict__ Wv, const float* __restrict__ scal,
                       unsigned short* __restrict__ Ut2){
  int hh=blockIdx.x, tile=blockIdx.y;
  int i0=(tile>>2)*64, d0=(tile&3)*64;
  __shared__ float As[64][33]; __shared__ float Bs[32][64];
  int t=threadIdx.x, tn=t&15, tm=t>>4;
  float acc[4][4]={};
  for(int k0=0;k0<256;k0+=32){
    { int kk=t&31, rr=t>>5;
      #pragma unroll
      for(int p=0;p<8;p++){ int r=rr+p*8;
        As[r][kk] = Wq[(size_t)(i0+r)*PJ + hh*256 + k0+kk]; } }
    { int kr=t>>6, cc=t&63;
      #pragma unroll
      for(int p=0;p<8;p++){ int k=kr+p*4;
        Bs[k][cc] = kvs[(size_t)hh*65536 + (k0+k)*256 + d0+cc]; } }
    __syncthreads();
    for(int k=0;k<32;k++){
      float a[4], b[4];
      #pragma unroll
      for(int i=0;i<4;i++) a[i]=As[tm*4+i][k];
      #pragma unroll
      for(int j=0;j<4;j++) b[j]=Bs[k][tn*4+j];
      #pragma unroll
      for(int i=0;i<4;i++)
        #pragma unroll
        for(int j=0;j<4;j++) acc[i][j] += a[i]*b[j];
    }
    __syncthreads();
  }
  float sc = scal[0];
  #pragma unroll
  for(int i=0;i<4;i++)
    #pragma unroll
    for(int j=0;j<4;j++){
      int ii=i0+tm*4+i, d=d0+tn*4+j;
      float val = sc*acc[i][j] + FN*Wv[(size_t)ii*PJ + hh*256 + d];
      Ut2[((size_t)(d>>6)*4 + (ii>>6))*16384 + ((size_t)hh*64 + (d&63))*64 + (ii&63)] = f2bf(val);
    }
}

// ---------------- per-head vectors -----------------------------------------
__global__ void head_vecs(const float* __restrict__ Wq, const float* __restrict__ bq,
                          const float* __restrict__ bv, const float* __restrict__ kvs,
                          const float* __restrict__ ksum, const float* __restrict__ scal,
                          float* __restrict__ uvec, float* __restrict__ wvec,
                          float* __restrict__ cvec){
  int hh=blockIdx.x, t=threadIdx.x;
  float scale=scal[0];
  __shared__ float bqs[256], kss[256];
  __shared__ float sh4[4];
  bqs[t]=bq[hh*256+t]; kss[t]=ksum[hh*256+t];
  __syncthreads();
  float su=0.f;
  for(int m=0;m<256;m++) su += bqs[m]*kvs[(size_t)hh*65536 + m*256 + t];
  uvec[hh*256+t] = scale*su + FN*bv[hh*256+t];
  float sw=0.f;
  for(int m=0;m<256;m++) sw += Wq[(size_t)t*PJ + hh*256 + m]*kss[m];
  wvec[hh*256+t] = scale*sw;
  float pc = bqs[t]*kss[t];
  float total = block_reduce(pc, sh4);
  if(t==0) cvec[hh] = scale*total + FN;
}

// ---------------- denom (reciprocal), bf16 h input (R10-proven) ------------
__global__ void denom_k(const unsigned short* __restrict__ hb, const float* __restrict__ wvec,
                        const float* __restrict__ cvec, float* __restrict__ denom, int M){
  __shared__ float wvl[1024];
  for(int i=threadIdx.x;i<1024;i+=256) wvl[i]=wvec[i];
  __syncthreads();
  int lane=threadIdx.x&63, wv=threadIdx.x>>6;
  int row=blockIdx.x*4+wv;
  if(row>=M) return;
  ushort4 hv = *(const ushort4*)(hb + (size_t)row*HID + lane*4);
  float h0=bf2f(hv.x), h1=bf2f(hv.y), h2=bf2f(hv.z), h3=bf2f(hv.w);
  float p[4];
  #pragma unroll
  for(int hh=0;hh<4;hh++){
    const float* wl = wvl + hh*256 + lane*4;
    p[hh] = h0*wl[0] + h1*wl[1] + h2*wl[2] + h3*wl[3];
  }
  #pragma unroll
  for(int hh=0;hh<4;hh++) p[hh]=wave_reduce(p[hh]);
  if(lane==0){
    #pragma unroll
    for(int hh=0;hh<4;hh++) denom[(size_t)row*4+hh] = 1.0f/(p[hh]+cvec[hh]);
  }
}

// ---------------- attn (R10-proven): BM=128, strips of 64, 8 waves 4x2 -----
__global__ __launch_bounds__(512,4)
void attn_mfma(const unsigned short* __restrict__ hb, const unsigned short* __restrict__ Ut2,
               const float* __restrict__ uvec, const float* __restrict__ rden,
               unsigned short* __restrict__ outp){
  __shared__ __align__(16) unsigned char smem[38912];
  unsigned short (*bs)[72] = (unsigned short(*)[72])smem;   // 256 x 72
  float (*red)[64] = (float(*)[64])smem;                    // overlay after loop
  float (*rsh)[4]  = (float(*)[4])(smem + 36864);           // 128 x 4
  int bm = blockIdx.x*128;
  int st = blockIdx.y;
  int t = threadIdx.x, w = t>>6, lane = t&63;
  int wr = w>>1, wc = w&1;
  int nst = t>>1, koff = (t&1)*32;

  f32x16 acc[4];
  #pragma unroll
  for(int j=0;j<4;j++)
    #pragma unroll
    for(int e=0;e<16;e++) acc[j][e]=0.f;

  { int r = t>>2, h2 = t&3;
    rsh[r][h2] = (bm+r<NN) ? rden[(size_t)(bm+r)*4+h2] : 1.0f; }

  const unsigned short* tb0 = Ut2 + (size_t)st*4*16384;
  u16x8 breg[4];
  #pragma unroll
  for(int i=0;i<4;i++) breg[i] = *(const u16x8*)(tb0 + (size_t)t*32 + i*8);

  int arow = bm + wr*32 + (lane&31); if(arow >= NN) arow = NN-1;
  const unsigned short* ap = hb + (size_t)arow*HID + (lane>>5)*8;

  #pragma unroll
  for(int kb=0;kb<4;kb++){
    __syncthreads();
    #pragma unroll
    for(int i=0;i<4;i++) *(u16x8*)&bs[nst][koff + i*8] = breg[i];
    __syncthreads();
    if(kb<3){
      const unsigned short* tn2 = Ut2 + ((size_t)st*4 + kb+1)*16384;
      #pragma unroll
      for(int i=0;i<4;i++) breg[i] = *(const u16x8*)(tn2 + (size_t)t*32 + i*8);
    }
    i32x4 a[4];
    #pragma unroll
    for(int ks=0;ks<4;ks++) a[ks] = *(const i32x4*)(ap + kb*64 + ks*16);
    #pragma unroll
    for(int ks=0;ks<4;ks++){
      int kc = ks*16 + (lane>>5)*8;
      #pragma unroll
      for(int j=0;j<4;j++){
        i32x4 b = *(const i32x4*)&bs[wc*128 + j*32 + (lane&31)][kc];
        mfma32(acc[j], a[ks], b);
      }
    }
  }
  float uv[4];
  #pragma unroll
  for(int j=0;j<4;j++)
    uv[j] = uvec[(wc*2 + (j>>1))*256 + st*64 + (j&1)*32 + (lane&31)];
  __syncthreads();
  if(wc==1){
    #pragma unroll
    for(int r=0;r<16;r++){
      int row = wr*32 + (r&3) + ((r>>2)<<3) + ((lane>>5)<<2);
      float d0 = rsh[row][2], d1 = rsh[row][3];
      red[row][lane&31]      = (acc[0][r]+uv[0])*d0 + (acc[2][r]+uv[2])*d1;
      red[row][32+(lane&31)] = (acc[1][r]+uv[1])*d0 + (acc[3][r]+uv[3])*d1;
    }
  }
  __syncthreads();
  if(wc==0){
    #pragma unroll
    for(int r=0;r<16;r++){
      int row = wr*32 + (r&3) + ((r>>2)<<3) + ((lane>>5)<<2);
      int gr = bm + row;
      if(gr < NN){
        float d0 = rsh[row][0], d1 = rsh[row][1];
        float v0 = ((acc[0][r]+uv[0])*d0 + (acc[2][r]+uv[2])*d1 + red[row][lane&31])      * 0.25f;
        float v1 = ((acc[1][r]+uv[1])*d0 + (acc[3][r]+uv[3])*d1 + red[row][32+(lane&31)]) * 0.25f;
        const unsigned short* hres = hb + (size_t)gr*HID + st*64;
        unsigned short* dst = outp + (size_t)gr*HID + st*64;
        dst[lane&31]      = f2bf((v0 + bf2f(hres[lane&31])) * 0.5f);
        dst[32+(lane&31)] = f2bf((v1 + bf2f(hres[32+(lane&31)])) * 0.5f);
      }
    }
  }
}

extern "C" void kernel_launch(void* const* d_in, const int* in_sizes, int n_in,
                              void* d_out, int out_size, void* d_ws, size_t ws_size,
                              hipStream_t stream){
  const float* x    = (const float*)d_in[0];
  const float* fc_w = (const float*)d_in[1];
  const float* fc_b = (const float*)d_in[2];
  const float* ln0g = (const float*)d_in[3];
  const float* ln0b = (const float*)d_in[4];
  float* out = (float*)d_out;

  float* W = (float*)d_ws;
  size_t o=0;
  unsigned short* hpre = (unsigned short*)(W+o); o+=(size_t)NN*HID/2;   // bf16 pre-LN
  unsigned short* hb   = (unsigned short*)(W+o); o+=(size_t)NN*HID/2;
  unsigned short* ht   = (unsigned short*)(W+o); o+=(size_t)HID*KTP/2;
  unsigned short* FWT2 = (unsigned short*)(W+o); o+=(size_t)8*16384/2 + 8;
  unsigned short* Ut2  = (unsigned short*)(W+o); o+=(size_t)16*16384/2 + 8;
  float* gramp= W+o; o+=(size_t)3*NCH*16384;
  float* G    = W+o; o+=65536;
  float* gw   = W+o; o+=3*262144;
  float* svec = W+o; o+=256;
  float* avec = W+o; o+=3072;
  float* trp  = W+o; o+=128;
  float* scal = W+o; o+=16;
  float* ksum = W+o; o+=1024;
  float* kvs  = W+o; o+=262144;
  float* uvec = W+o; o+=1024;
  float* wvec = W+o; o+=1024;
  float* cvec = W+o; o+=8;
  float* denB = W+o; o+=(size_t)NN*4;
  (void)ws_size; (void)in_sizes; (void)n_in; (void)out_size;

  dim3 blk(256);
  wconv<<<dim3(512),blk,0,stream>>>(fc_w, FWT2);
  ffn_gemm<<<dim3(391),dim3(512),0,stream>>>(x, FWT2, fc_b, ln0g, ln0b, hb);

  for(int L=0; L<2; L++){
    const float* wq = (const float*)d_in[5+L*8+0];
    const float* bq = (const float*)d_in[5+L*8+1];
    const float* wk = (const float*)d_in[5+L*8+2];
    const float* bk = (const float*)d_in[5+L*8+3];
    const float* wv = (const float*)d_in[5+L*8+4];
    const float* bv = (const float*)d_in[5+L*8+5];
    const float* lng= (const float*)d_in[5+L*8+6];
    const float* lnb= (const float*)d_in[5+L*8+7];

    transpose_h<<<dim3(784,4),blk,0,stream>>>(hb, ht);
    gram_mfma<<<dim3(3,NCH),blk,0,stream>>>(ht, gramp);
    gram_post<<<dim3(448),blk,0,stream>>>(gramp, G, ht, svec);
    gw_gemm3<<<dim3(4,16,3),blk,0,stream>>>(G, wq, wk, wv, gw);
    wtr<<<dim3(140),blk,0,stream>>>(wq, wk, wv, svec, gw, avec, trp);
    kvs_k<<<dim3(4,17),blk,0,stream>>>(wk, gw+2*262144, avec, bk, bv, kvs,
                                       trp, bq, ksum, scal);
    u_gemm<<<dim3(4,16),blk,0,stream>>>(wq, kvs, wv, scal, Ut2);
    head_vecs<<<dim3(4),blk,0,stream>>>(wq,bq,bv,kvs,ksum,scal,uvec,wvec,cvec);
    denom_k<<<dim3(12500),blk,0,stream>>>(hb, wvec, cvec, denB, NN);
    attn_mfma<<<dim3(391,4),dim3(512),0,stream>>>(hb, Ut2, uvec, denB, hpre);
    ln_relu2b<<<dim3(12500),blk,0,stream>>>(hpre, lng, lnb,
                                            L ? (unsigned short*)nullptr : hb,
                                            L ? out : (float*)nullptr, NN);
  }
}